// Round 1
// baseline (16389.192 us; speedup 1.0000x reference)
//
#include <hip/hip_runtime.h>

// ---------------- problem constants ----------------
#define HND    233            // hidden size H
#define NL     6              // layers L
#define GPL    30             // workgroups per layer
#define UMAX   8              // hidden units per WG (30*8 = 240 >= 233)
#define RUMAX  32             // gate rows per WG (4*UMAX)
#define TSTEPS 16             // LSTM scan length (= B of reference!)
#define FSTEPS 96             // autoregressive steps (= F)
#define NSLOT  (TSTEPS*FSTEPS)
#define CDIM   12             // token dim C
#define G4H    (4*HND)        // 932
#define ROWLEN1 468           // padded (H+H)=466 -> 468  (stride%32=20: conflict-free b128)
#define ROWLEN0 252           // padded (C+H)=245 -> 252  (stride%32=28: conflict-free b128)
#define BLOCK  128
#define AG __HIP_MEMORY_SCOPE_AGENT

__device__ __forceinline__ float sigf(float x) { return 1.f / (1.f + expf(-x)); }

// All-block wait until p[i] >= target for i in [0,n). Acquire semantics per thread.
__device__ __forceinline__ void wait_ge(int* p, int n, int target) {
  long guard = 0;
  for (;;) {
    int pred = 1;
    if ((int)threadIdx.x < n) {
      int v = __hip_atomic_load(p + threadIdx.x, __ATOMIC_ACQUIRE, AG);
      pred = (v >= target);
    }
    if (__syncthreads_and(pred)) return;
    __builtin_amdgcn_s_sleep(1);
    if (++guard > (1L << 24)) return;   // safety bail: avoid infinite hang on bug
  }
}

__global__ void init_kernel(const float* __restrict__ X, float* __restrict__ xin0,
                            int* __restrict__ flags) {
  int i = threadIdx.x;
  if (i < 256) flags[i] = 0;
  if (i < TSTEPS * CDIM) {
    int t = i / CDIM, c = i % CDIM;
    // seed = window column 95: X[t][95][c], X is (16,96,12)
    xin0[i] = X[(size_t)(t * 96 + 95) * CDIM + c];
  }
}

// grid: NL*GPL layer blocks + 1 head block. 128 threads each.
__global__ void __launch_bounds__(BLOCK) lstm_pipe(
    const float* __restrict__ Wih0, const float* __restrict__ Wih,
    const float* __restrict__ Whh,  const float* __restrict__ bih,
    const float* __restrict__ bhh,  const float* __restrict__ Wl,
    const float* __restrict__ bl,   float* __restrict__ out,
    float* __restrict__ hout, float* __restrict__ xin0, int* __restrict__ flags) {
  __shared__ float w[RUMAX * ROWLEN1];   // per-WG weight rows [Wih | Whh | pad]
  __shared__ float vin[ROWLEN1];         // [x | hprev | pad]
  __shared__ float bias[RUMAX];
  __shared__ float part[RUMAX * 4];
  __shared__ float gates[RUMAX];
  __shared__ float cst[UMAX];

  const int tid = threadIdx.x;
  const int bid = blockIdx.x;

  if (bid == NL * GPL) {
    // ---------------- head: new = h6 @ Wl.T + bl ----------------
    for (int i = tid; i < CDIM * HND; i += BLOCK) w[i] = Wl[i];
    __syncthreads();
    for (int s = 0; s < NSLOT; ++s) {
      wait_ge(flags + 5 * 32, GPL, s + 1);
      for (int k = tid; k < HND; k += BLOCK)
        vin[k] = __hip_atomic_load(hout + ((size_t)5 * NSLOT + s) * HND + k,
                                   __ATOMIC_RELAXED, AG);
      __syncthreads();
      if (tid < CDIM) {
        const float* wr = w + tid * HND;
        float a0 = 0.f, a1 = 0.f, a2 = 0.f, a3 = 0.f;
        int k = 0;
        for (; k + 4 <= HND; k += 4) {
          a0 = fmaf(wr[k], vin[k], a0);
          a1 = fmaf(wr[k + 1], vin[k + 1], a1);
          a2 = fmaf(wr[k + 2], vin[k + 2], a2);
          a3 = fmaf(wr[k + 3], vin[k + 3], a3);
        }
        for (; k < HND; ++k) a0 = fmaf(wr[k], vin[k], a0);
        float v = a0 + a1 + a2 + a3 + bl[tid];
        int t = s & 15, f = s >> 4;
        out[(size_t)t * FSTEPS * CDIM + f * CDIM + tid] = v;   // out[b=t][f][c]
        if (s + TSTEPS < NSLOT)
          __hip_atomic_store(xin0 + (size_t)(s + TSTEPS) * CDIM + tid, v,
                             __ATOMIC_RELAXED, AG);
      }
      __threadfence();
      __syncthreads();
      if (tid == 0) __hip_atomic_store(flags + NL * 32, s + 1, __ATOMIC_RELEASE, AG);
    }
    return;
  }

  // ---------------- layer workgroup ----------------
  const int l = bid / GPL, g = bid % GPL;
  const int j0 = g * UMAX;
  const int U = min(UMAX, HND - j0);          // last WG: 1 unit
  const int RU = 4 * U;
  const int Din = (l == 0) ? CDIM : HND;
  const int rowlen = (l == 0) ? ROWLEN0 : ROWLEN1;
  const int rowlen4 = rowlen >> 2;
  const int KC4 = (rowlen4 + 3) >> 2;

  // ---- load weights into LDS: local row r = u*4 + gate, global row = gate*H + j0 + u
  const float* wih_l = (l == 0) ? Wih0 : (Wih + (size_t)(l - 1) * G4H * HND);
  const float* whh_l = Whh + (size_t)l * G4H * HND;
  for (int idx = tid; idx < RU * rowlen; idx += BLOCK) {
    int r = idx / rowlen, k = idx - r * rowlen;
    int u = r >> 2, gt = r & 3;
    int grow = gt * HND + j0 + u;
    float v = 0.f;
    if (k < Din) v = wih_l[(size_t)grow * Din + k];
    else if (k < Din + HND) v = whh_l[(size_t)grow * HND + (k - Din)];
    w[r * rowlen + k] = v;
  }
  for (int r = tid; r < RU; r += BLOCK) {
    int u = r >> 2, gt = r & 3;
    int grow = gt * HND + j0 + u;
    bias[r] = bih[l * G4H + grow] + bhh[l * G4H + grow];
  }
  for (int k = Din + HND + tid; k < rowlen; k += BLOCK) vin[k] = 0.f;  // pad, once
  __syncthreads();

  const bool active = tid < 4 * RU;
  const int r = active ? (tid % RU) : 0;      // row, 4-way k split
  const int j = active ? (tid / RU) : 0;
  const int c0 = j * KC4;
  const int c1 = min(c0 + KC4, rowlen4);
  const float4* wr4 = (const float4*)(w + r * rowlen);
  const float4* vi4 = (const float4*)vin;
  int* ownflags = flags + l * 32;
  int* prevflags = (l > 0) ? (flags + (l - 1) * 32) : flags;

  for (int s = 0; s < NSLOT; ++s) {
    const int t = s & 15;
    // ---- input vector x -> vin[0..Din)
    if (l == 0) {
      if (s >= TSTEPS) wait_ge(flags + NL * 32, 1, s - TSTEPS + 1);
      if (tid < CDIM)
        vin[tid] = __hip_atomic_load(xin0 + (size_t)s * CDIM + tid, __ATOMIC_RELAXED, AG);
    } else {
      wait_ge(prevflags, GPL, s + 1);
      for (int k = tid; k < HND; k += BLOCK)
        vin[k] = __hip_atomic_load(hout + ((size_t)(l - 1) * NSLOT + s) * HND + k,
                                   __ATOMIC_RELAXED, AG);
    }
    // ---- hprev -> vin[Din..Din+H)  (h resets each outer step: t==0 -> zeros)
    if (t > 0) {
      wait_ge(ownflags, GPL, s);   // flag value s means slot s-1 complete
      for (int k = tid; k < HND; k += BLOCK)
        vin[Din + k] = __hip_atomic_load(hout + ((size_t)l * NSLOT + (s - 1)) * HND + k,
                                         __ATOMIC_RELAXED, AG);
    } else {
      for (int k = tid; k < HND; k += BLOCK) vin[Din + k] = 0.f;
    }
    __syncthreads();

    // ---- matvec partials: gates = W_row . vin
    if (active) {
      float a0 = 0.f, a1 = 0.f;
      int c = c0;
      for (; c + 2 <= c1; c += 2) {
        float4 x0 = wr4[c], y0 = vi4[c];
        float4 x1 = wr4[c + 1], y1 = vi4[c + 1];
        a0 = fmaf(x0.w, y0.w, fmaf(x0.z, y0.z, fmaf(x0.y, y0.y, fmaf(x0.x, y0.x, a0))));
        a1 = fmaf(x1.w, y1.w, fmaf(x1.z, y1.z, fmaf(x1.y, y1.y, fmaf(x1.x, y1.x, a1))));
      }
      if (c < c1) {
        float4 x0 = wr4[c], y0 = vi4[c];
        a0 = fmaf(x0.w, y0.w, fmaf(x0.z, y0.z, fmaf(x0.y, y0.y, fmaf(x0.x, y0.x, a0))));
      }
      part[r * 4 + j] = a0 + a1;
    }
    __syncthreads();
    if (tid < RU)
      gates[tid] = part[tid * 4] + part[tid * 4 + 1] + part[tid * 4 + 2] +
                   part[tid * 4 + 3] + bias[tid];
    __syncthreads();

    // ---- cell update for own units
    if (tid < U) {
      float gi = gates[tid * 4 + 0], gf = gates[tid * 4 + 1];
      float gg = gates[tid * 4 + 2], go = gates[tid * 4 + 3];
      float cp = (t == 0) ? 0.f : cst[tid];
      float cn = sigf(gf) * cp + sigf(gi) * tanhf(gg);
      float hn = sigf(go) * tanhf(cn);
      cst[tid] = cn;
      __hip_atomic_store(hout + ((size_t)l * NSLOT + s) * HND + j0 + tid, hn,
                         __ATOMIC_RELAXED, AG);
    }
    __threadfence();
    __syncthreads();
    if (tid == 0) __hip_atomic_store(ownflags + g, s + 1, __ATOMIC_RELEASE, AG);
  }
}

extern "C" void kernel_launch(void* const* d_in, const int* in_sizes, int n_in,
                              void* d_out, int out_size, void* d_ws, size_t ws_size,
                              hipStream_t stream) {
  const float* X    = (const float*)d_in[0];
  const float* Wih0 = (const float*)d_in[1];
  const float* Wih  = (const float*)d_in[2];
  const float* Whh  = (const float*)d_in[3];
  const float* bih  = (const float*)d_in[4];
  const float* bhh  = (const float*)d_in[5];
  const float* Wl   = (const float*)d_in[6];
  const float* bl   = (const float*)d_in[7];

  // workspace layout: [flags: 1KB][hout: 6*1536*233 f32][xin0: 1536*12 f32] ~= 8.66 MB
  int* flags  = (int*)d_ws;
  float* hout = (float*)((char*)d_ws + 1024);
  float* xin0 = hout + (size_t)NL * NSLOT * HND;

  init_kernel<<<1, 256, 0, stream>>>(X, xin0, flags);
  lstm_pipe<<<NL * GPL + 1, BLOCK, 0, stream>>>(Wih0, Wih, Whh, bih, bhh, Wl, bl,
                                                (float*)d_out, hout, xin0, flags);
}

// Round 2
// 6104.406 us; speedup vs baseline: 2.6848x; 2.6848x over previous
//
#include <hip/hip_runtime.h>

// ---------------- problem constants ----------------
#define HND    233            // hidden size H
#define NL     6              // layers L
#define GPL    30             // workgroups per layer
#define UMAX   8              // hidden units per WG (30*8 = 240 >= 233)
#define RUMAX  32             // gate rows per WG (4*UMAX)
#define TSTEPS 16             // LSTM scan length (= B of reference)
#define FSTEPS 96             // autoregressive steps (= F)
#define NSLOT  (TSTEPS*FSTEPS)
#define CDIM   12             // token dim C
#define G4H    (4*HND)        // 932
#define ROWLEN1 468           // padded (H+H)=466 -> 468
#define ROWLEN0 252           // padded (C+H)=245 -> 252
#define BLOCK  128
#define AG __HIP_MEMORY_SCOPE_AGENT
#define SENT 0x7FBADBADu      // NaN bit pattern: real data can never equal this

__device__ __forceinline__ float sigf(float x) { return 1.f / (1.f + expf(-x)); }

// Re-poison hout/xin0 to sentinel each run (write-once dataflow), seed xin0[s<16].
__global__ void init_kernel(const float* __restrict__ X,
                            unsigned* __restrict__ hout_u,
                            unsigned* __restrict__ xin_u) {
  size_t i = (size_t)blockIdx.x * blockDim.x + threadIdx.x;
  size_t stride = (size_t)gridDim.x * blockDim.x;
  const size_t nh = (size_t)NL * NSLOT * HND;
  for (size_t k = i; k < nh; k += stride) hout_u[k] = SENT;
  for (size_t k = i; k < (size_t)NSLOT * CDIM; k += stride) {
    int s = (int)(k / CDIM), c = (int)(k % CDIM);
    if (s < TSTEPS) {
      // seed = window column 95: X[t=s][95][c], X is (16,96,12)
      ((float*)xin_u)[k] = X[((size_t)s * 96 + 95) * CDIM + c];
    } else {
      xin_u[k] = SENT;
    }
  }
}

// grid: NL*GPL layer blocks + 1 head block. 128 threads each.
__global__ void __launch_bounds__(BLOCK) lstm_pipe(
    const float* __restrict__ Wih0, const float* __restrict__ Wih,
    const float* __restrict__ Whh,  const float* __restrict__ bih,
    const float* __restrict__ bhh,  const float* __restrict__ Wl,
    const float* __restrict__ bl,   float* __restrict__ out,
    float* __restrict__ hout, float* __restrict__ xin0) {
  __shared__ float w[RUMAX * ROWLEN1];   // per-WG weight rows [Wih | Whh | pad]
  __shared__ float vin[ROWLEN1];         // [x | hprev | pad]
  __shared__ float bias[RUMAX];
  __shared__ float part[RUMAX * 4];

  const int tid = threadIdx.x;
  const int bid = blockIdx.x;
  unsigned* hout_u = (unsigned*)hout;
  unsigned* xin_u  = (unsigned*)xin0;

  if (bid == NL * GPL) {
    // ---------------- head: new = h6 @ Wl.T + bl ----------------
    for (int i = tid; i < CDIM * HND; i += BLOCK) w[i] = Wl[i];
    const float blv = (tid < CDIM) ? bl[tid] : 0.f;
    __syncthreads();
    for (int s = 0; s < NSLOT; ++s) {
      const unsigned* src = hout_u + ((size_t)5 * NSLOT + s) * HND;
      unsigned vbuf[2];
      long guard = 0;
      for (;;) {
        bool ok = true;
        #pragma unroll
        for (int q = 0; q < 2; ++q) {
          int idx = tid + q * BLOCK;
          if (idx < HND) {
            unsigned v = __hip_atomic_load(src + idx, __ATOMIC_RELAXED, AG);
            vbuf[q] = v;
            ok = ok && (v != SENT);
          }
        }
        if (__syncthreads_and(ok)) break;
        __builtin_amdgcn_s_sleep(1);
        if (++guard > (1L << 21)) break;   // safety bail
      }
      #pragma unroll
      for (int q = 0; q < 2; ++q) {
        int idx = tid + q * BLOCK;
        if (idx < HND) vin[idx] = __uint_as_float(vbuf[q]);
      }
      __syncthreads();
      if (tid < CDIM) {
        const float* wr = w + tid * HND;
        float a0 = 0.f, a1 = 0.f, a2 = 0.f, a3 = 0.f;
        int k = 0;
        for (; k + 4 <= HND; k += 4) {
          a0 = fmaf(wr[k],     vin[k],     a0);
          a1 = fmaf(wr[k + 1], vin[k + 1], a1);
          a2 = fmaf(wr[k + 2], vin[k + 2], a2);
          a3 = fmaf(wr[k + 3], vin[k + 3], a3);
        }
        for (; k < HND; ++k) a0 = fmaf(wr[k], vin[k], a0);
        float v = a0 + a1 + a2 + a3 + blv;
        if (s + TSTEPS < NSLOT)
          __hip_atomic_store((float*)(xin_u) + (size_t)(s + TSTEPS) * CDIM + tid, v,
                             __ATOMIC_RELAXED, AG);
        int t = s & 15, f = s >> 4;
        out[(size_t)t * FSTEPS * CDIM + f * CDIM + tid] = v;   // out[b=t][f][c]
      }
      // next slot's poll barrier protects vin reuse
    }
    return;
  }

  // ---------------- layer workgroup ----------------
  const int l = bid / GPL, g = bid % GPL;
  const int j0 = g * UMAX;
  const int U = min(UMAX, HND - j0);          // last WG: 1 unit
  const int RU = 4 * U;
  const int Din = (l == 0) ? CDIM : HND;
  const int rowlen = (l == 0) ? ROWLEN0 : ROWLEN1;
  const int rowlen4 = rowlen >> 2;
  const int KC4 = (rowlen4 + 3) >> 2;

  // ---- load weights into LDS: local row r = u*4 + gate, global row = gate*H + j0 + u
  const float* wih_l = (l == 0) ? Wih0 : (Wih + (size_t)(l - 1) * G4H * HND);
  const float* whh_l = Whh + (size_t)l * G4H * HND;
  for (int idx = tid; idx < RU * rowlen; idx += BLOCK) {
    int r = idx / rowlen, k = idx - r * rowlen;
    int u = r >> 2, gt = r & 3;
    int grow = gt * HND + j0 + u;
    float v = 0.f;
    if (k < Din) v = wih_l[(size_t)grow * Din + k];
    else if (k < Din + HND) v = whh_l[(size_t)grow * HND + (k - Din)];
    w[r * rowlen + k] = v;
  }
  for (int r = tid; r < RU; r += BLOCK) {
    int u = r >> 2, gt = r & 3;
    int grow = gt * HND + j0 + u;
    bias[r] = bih[l * G4H + grow] + bhh[l * G4H + grow];
  }
  for (int k = Din + HND + tid; k < rowlen; k += BLOCK) vin[k] = 0.f;  // pad, once
  __syncthreads();

  const bool active = tid < 4 * RU;
  const int r = active ? (tid % RU) : 0;      // row, 4-way k split
  const int j = active ? (tid / RU) : 0;
  const int c0 = j * KC4;
  const int c1 = min(c0 + KC4, rowlen4);
  const float4* wr4 = (const float4*)(w + r * rowlen);
  const float4* vi4 = (const float4*)vin;

  float cstate = 0.f;                         // per-unit c (tid < U owns unit j0+tid)

  for (int s = 0; s < NSLOT; ++s) {
    const int t = s & 15;
    const int P = Din + ((t > 0) ? HND : 0);  // words to poll this slot
    const unsigned* base_x = (l == 0) ? (xin_u + (size_t)s * CDIM)
                                      : (hout_u + ((size_t)(l - 1) * NSLOT + s) * HND);
    const unsigned* base_h = hout_u + ((size_t)l * NSLOT + (s - 1)) * HND;

    // ---- poll the data itself (write-once; sentinel => not yet produced)
    unsigned vbuf[4];
    long guard = 0;
    for (;;) {
      bool ok = true;
      #pragma unroll
      for (int q = 0; q < 4; ++q) {
        int idx = tid + q * BLOCK;
        if (idx < P) {
          const unsigned* p = (idx < Din) ? (base_x + idx) : (base_h + (idx - Din));
          unsigned v = __hip_atomic_load(p, __ATOMIC_RELAXED, AG);
          vbuf[q] = v;
          ok = ok && (v != SENT);
        }
      }
      if (__syncthreads_and(ok)) break;
      __builtin_amdgcn_s_sleep(1);
      if (++guard > (1L << 21)) break;   // safety bail
    }
    #pragma unroll
    for (int q = 0; q < 4; ++q) {
      int idx = tid + q * BLOCK;
      if (idx < P) vin[idx] = __uint_as_float(vbuf[q]);
    }
    if (t == 0) {
      for (int k = Din + tid; k < Din + HND; k += BLOCK) vin[k] = 0.f;
    }
    __syncthreads();

    // ---- matvec partials: gates = W_row . vin
    if (active) {
      float a0 = 0.f, a1 = 0.f;
      int c = c0;
      for (; c + 2 <= c1; c += 2) {
        float4 x0 = wr4[c], y0 = vi4[c];
        float4 x1 = wr4[c + 1], y1 = vi4[c + 1];
        a0 = fmaf(x0.w, y0.w, fmaf(x0.z, y0.z, fmaf(x0.y, y0.y, fmaf(x0.x, y0.x, a0))));
        a1 = fmaf(x1.w, y1.w, fmaf(x1.z, y1.z, fmaf(x1.y, y1.y, fmaf(x1.x, y1.x, a1))));
      }
      if (c < c1) {
        float4 x0 = wr4[c], y0 = vi4[c];
        a0 = fmaf(x0.w, y0.w, fmaf(x0.z, y0.z, fmaf(x0.y, y0.y, fmaf(x0.x, y0.x, a0))));
      }
      part[r * 4 + j] = a0 + a1;
    }
    __syncthreads();

    // ---- cell update: each of U threads reduces its own 4 gates directly
    if (tid < U) {
      float gg[4];
      #pragma unroll
      for (int gt = 0; gt < 4; ++gt) {
        int rr = tid * 4 + gt;
        gg[gt] = part[rr * 4] + part[rr * 4 + 1] + part[rr * 4 + 2] +
                 part[rr * 4 + 3] + bias[rr];
      }
      float cp = (t == 0) ? 0.f : cstate;
      float cn = sigf(gg[1]) * cp + sigf(gg[0]) * tanhf(gg[2]);
      float hn = sigf(gg[3]) * tanhf(cn);
      cstate = cn;
      __hip_atomic_store(hout + ((size_t)l * NSLOT + s) * HND + j0 + tid, hn,
                         __ATOMIC_RELAXED, AG);
    }
    // no fence, no flag: consumers poll the data words themselves.
    // next slot's poll barrier protects vin/part reuse.
  }
}

extern "C" void kernel_launch(void* const* d_in, const int* in_sizes, int n_in,
                              void* d_out, int out_size, void* d_ws, size_t ws_size,
                              hipStream_t stream) {
  const float* X    = (const float*)d_in[0];
  const float* Wih0 = (const float*)d_in[1];
  const float* Wih  = (const float*)d_in[2];
  const float* Whh  = (const float*)d_in[3];
  const float* bih  = (const float*)d_in[4];
  const float* bhh  = (const float*)d_in[5];
  const float* Wl   = (const float*)d_in[6];
  const float* bl   = (const float*)d_in[7];

  // workspace layout: [hout: 6*1536*233 f32][xin0: 1536*12 f32] ~= 8.66 MB
  float* hout = (float*)d_ws;
  float* xin0 = hout + (size_t)NL * NSLOT * HND;

  init_kernel<<<2048, 256, 0, stream>>>(X, (unsigned*)hout, (unsigned*)xin0);
  lstm_pipe<<<NL * GPL + 1, BLOCK, 0, stream>>>(Wih0, Wih, Whh, bih, bhh, Wl, bl,
                                                (float*)d_out, hout, xin0);
}